// Round 23
// baseline (1354.188 us; speedup 1.0000x reference)
//
#include <hip/hip_runtime.h>

#define H 1024
#define SEQ 2048
#define MROWS 16384           // 8 * 2048
#define KD 1024               // GEMM K dim
#define NT32 32               // K-tiles of 32
#define EPW 72                // epilogue LDS stride (f16)

typedef _Float16 f16;
typedef _Float16 f16x8 __attribute__((ext_vector_type(8)));
typedef float f32x4 __attribute__((ext_vector_type(4)));

__device__ __forceinline__ float gate_fn(float x) {
    float s = 1.0f / (1.0f + __expf(-x));
    return fminf(fmaxf(1.2f * s - 0.1f, 0.0f), 1.0f);
}

// fragment-major state layout: element (row,k) ->
//   S'[row>>4][k>>5][lane][j],  lane=(row&15)|(((k>>3)&3)<<4), j=k&7
// flat elems: ((row>>4)*32 + (k>>5))*512 + lane*8 + j
// A wave's MFMA A-fragment (16 rows x 32 k) = ONE contiguous 1KB block.
__device__ __forceinline__ size_t frag_off(int row, int k) {
    return ((size_t)((row >> 4) * 32 + (k >> 5))) * 512
         + (size_t)((((row & 15) | (((k >> 3) & 3) << 4)) << 3) + (k & 7));
}

__device__ __forceinline__ void gload_lds16(const void* g, void* lds) {
    __builtin_amdgcn_global_load_lds(
        (const __attribute__((address_space(1))) unsigned int*)g,
        (__attribute__((address_space(3))) unsigned int*)lds, 16, 0, 0);
}

// ---------------- fp32 -> fp16 convert (row-major, for proj A) ----------------
__global__ void k_f32_to_f16(const float* __restrict__ in, f16* __restrict__ out) {
    size_t i = ((size_t)blockIdx.x * blockDim.x + threadIdx.x) * 8;
    float4 v0 = *(const float4*)(in + i);
    float4 v1 = *(const float4*)(in + i + 4);
    f16x8 o;
    o[0] = (f16)v0.x; o[1] = (f16)v0.y; o[2] = (f16)v0.z; o[3] = (f16)v0.w;
    o[4] = (f16)v1.x; o[5] = (f16)v1.y; o[6] = (f16)v1.z; o[7] = (f16)v1.w;
    *(f16x8*)(out + i) = o;
}

// ---------------- transpose + convert: WT[n][k] = (f16)W[k][n] ----------------
__global__ void k_transpose_f16(const float* __restrict__ Wsrc, f16* __restrict__ WT,
                                int K, int N) {
    __shared__ float tile[32][33];
    int n0 = blockIdx.x * 32, k0 = blockIdx.y * 32;
    for (int i = threadIdx.y; i < 32; i += 8)
        tile[i][threadIdx.x] = Wsrc[(size_t)(k0 + i) * N + n0 + threadIdx.x];
    __syncthreads();
    for (int i = threadIdx.y; i < 32; i += 8)
        WT[(size_t)(n0 + i) * K + k0 + threadIdx.x] = (f16)tile[threadIdx.x][i];
}

// ---------------- proj GEMM (128x128, row-major A) ----------------
__global__ __launch_bounds__(256) void k_proj_gemm(const f16* __restrict__ A,
                                                   const f16* __restrict__ BT,
                                                   f16* __restrict__ P16) {
    __shared__ alignas(16) f16 Alds[128 * 32];
    __shared__ alignas(16) f16 Blds[128 * 32];
    const int tid = threadIdx.x;
    const int lane = tid & 63, wid = tid >> 6;
    const int l15 = lane & 15, l4 = lane >> 4;
    const int bm = blockIdx.x, bn = blockIdx.y;

    const f16* gA[2]; const f16* gB[2];
    char* ldsA[2]; char* ldsB[2];
#pragma unroll
    for (int it = 0; it < 2; ++it) {
        int c = it * 4 + wid;
        int row = c * 16 + (lane >> 2);
        int kch = (lane & 3) ^ ((row >> 1) & 3);
        gA[it] = A + (size_t)(bm * 128 + row) * KD + kch * 8;
        gB[it] = BT + (size_t)(bn * 128 + row) * KD + kch * 8;
        ldsA[it] = (char*)Alds + c * 1024;
        ldsB[it] = (char*)Blds + c * 1024;
    }

    int offA[2], offB[8];
#pragma unroll
    for (int m = 0; m < 2; ++m) {
        int row = wid * 32 + m * 16 + l15;
        offA[m] = row * 64 + ((l4 ^ ((row >> 1) & 3)) << 4);
    }
#pragma unroll
    for (int n = 0; n < 8; ++n) {
        int row = n * 16 + l15;
        offB[n] = row * 64 + ((l4 ^ ((row >> 1) & 3)) << 4);
    }

    f32x4 acc[2][8] = {};

    for (int kt = 0; kt < KD / 32; ++kt) {
        __syncthreads();
#pragma unroll
        for (int it = 0; it < 2; ++it) {
            gload_lds16(gA[it], ldsA[it]);
            gload_lds16(gB[it], ldsB[it]);
            gA[it] += 32; gB[it] += 32;
        }
        __syncthreads();
        f16x8 a[2], b[8];
#pragma unroll
        for (int m = 0; m < 2; ++m) a[m] = *(const f16x8*)((const char*)Alds + offA[m]);
#pragma unroll
        for (int n = 0; n < 8; ++n) b[n] = *(const f16x8*)((const char*)Blds + offB[n]);
#pragma unroll
        for (int n = 0; n < 8; ++n)
#pragma unroll
            for (int m = 0; m < 2; ++m)
                acc[m][n] = __builtin_amdgcn_mfma_f32_16x16x32_f16(a[m], b[n], acc[m][n], 0, 0, 0);
    }

#pragma unroll
    for (int m = 0; m < 2; ++m)
#pragma unroll
        for (int n = 0; n < 8; ++n) {
            int col = bn * 128 + n * 16 + l15;
#pragma unroll
            for (int r = 0; r < 4; ++r) {
                int row = bm * 128 + wid * 32 + m * 16 + l4 * 4 + r;
                P16[(size_t)row * H + col] = (f16)acc[m][n][r];
            }
        }
}

// ---------------- step 0 (state==0): writes S16 in FRAGMENT layout ----------------
__global__ void k_step0(const f16* __restrict__ P16, const float* __restrict__ by,
                        f16* __restrict__ S16) {
    size_t idx = ((size_t)blockIdx.x * blockDim.x + threadIdx.x) * 8;
    int row = (int)(idx >> 10);
    int d = (int)(idx & 1023);
    int s = row & (SEQ - 1);
    f16x8 p = {};
    if (s >= 15) p = *(const f16x8*)(P16 + (size_t)(row - 15) * H + d);
    float4 byc0 = *(const float4*)(by + d);
    float4 byc1 = *(const float4*)(by + d + 4);
    float4 byg0 = *(const float4*)(by + H + d);
    float4 byg1 = *(const float4*)(by + H + d + 4);
    f16x8 sv;
#pragma unroll
    for (int j = 0; j < 8; ++j) {
        float byc = (j < 4) ? ((const float*)&byc0)[j] : ((const float*)&byc1)[j - 4];
        float byg = (j < 4) ? ((const float*)&byg0)[j] : ((const float*)&byg1)[j - 4];
        float g = gate_fn(byg);
        float v = fmaxf(g * ((float)p[j] + byc), 0.f);
        sv[j] = (f16)v;
    }
    *(f16x8*)(S16 + frag_off(row, d)) = sv;
}

// ---------------- step GEMM: 4-wave blocks, 4 blocks/CU (convoy-stagger) ----------------
// A = state_f16 FRAGMENT layout; BT = WyT [2H][K] row-major. Block (bm,tb):
// rows bm*128..+128, cand cols tb*64..+64 + gates. 4 waves (2wr x 2wc), wave
// 64x64 (32c+32g): identical per-wave work to the 8-wave best kernel (4 A-frag
// coalesced 1KB loads, 4 swizzled B ds_reads, 16 MFMA, acc[4][4]=64 AGPR).
// Halving the block quarters the barrier-convoy width: 16 waves/CU now sit in
// 4 INDEPENDENT barrier domains (vs 2), so one block's waves MFMA while
// another's issue loads. LDS 36864B (B dbuf 2x8KB U epilogue 2x18KB) ->
// 4 blocks/CU; 120 regs -> 4 waves/SIMD. Cost: B L2 traffic x2 (+7us bound).
__global__ __launch_bounds__(256, 4) void k_step_gemm(const f16* __restrict__ A,
                                                      const f16* __restrict__ BT,
                                                      const f16* __restrict__ P16,
                                                      const float* __restrict__ by,
                                                      float* __restrict__ Out,
                                                      f16* __restrict__ Snext,
                                                      int stepi) {
    __shared__ alignas(16) char lds[36864];    // B dbuf 2x8KB; epilogue 2x18KB
    const int tid = threadIdx.x;
    const int lane = tid & 63, w = tid >> 6;
    const int l15 = lane & 15, l4 = lane >> 4;
    const int wr = w >> 1, wc = w & 1;

    // bijective XCD swizzle: 2048 wgs, 256/XCD, tb fastest (A-panel L2 reuse)
    const int orig = blockIdx.x;
    const int wg = (orig & 7) * 256 + (orig >> 3);
    const int bm = wg >> 4, tb = wg & 15;      // bm 0..127 (128-row panels)

    // B staging: 128 rows x 64B per K-tile = 512 16B-slots; thread t covers
    // slots t and t+256. Row = s>>2, source slot pre-XOR-swizzled.
    const int rB0 = tid >> 2, rB1 = 64 + (tid >> 2);
    const int sl0 = (tid & 3) ^ ((rB0 >> 1) & 3);
    const int sl1 = (tid & 3) ^ ((rB1 >> 1) & 3);
    const int rowB0 = tb * 64 + (rB0 & 63);                  // cand rows
    const int rowB1 = H + tb * 64 + (rB1 & 63);              // gate rows
    const char* pB0 = (const char*)BT + ((size_t)rowB0 * KD + sl0 * 8) * 2;
    const char* pB1 = (const char*)BT + ((size_t)rowB1 * KD + sl1 * 8) * 2;

    // A fragment pointers: row16 block = bm*8 + wr*4 + m; 1KB frags, lane*16B
    const char* ap[4];
#pragma unroll
    for (int m = 0; m < 4; ++m) {
        int r16 = bm * 8 + wr * 4 + m;
        ap[m] = (const char*)A + ((size_t)r16 * 32) * 1024 + lane * 16;
    }

#define STAGEB(bp) do { gload_lds16(pB0, (bp) + tid * 16); \
                        gload_lds16(pB1, (bp) + 4096 + tid * 16); \
                        pB0 += 64; pB1 += 64; } while (0)

    const int sx = (l4 ^ ((l15 >> 1) & 3)) << 4;
    int offB[4];
#pragma unroll
    for (int n = 0; n < 2; ++n) {
        offB[n]     = (wc * 32 + n * 16 + l15) * 64 + sx;            // cand rows 0..63
        offB[2 + n] = (64 + wc * 32 + n * 16 + l15) * 64 + sx;       // gate rows 64..127
    }

    f32x4 acc[4][4] = {};

    char* const buf0 = lds;
    char* const buf1 = lds + 8192;
    char* cb = buf0;
    char* nx = buf1;

    STAGEB(buf0);
    __syncthreads();

#pragma unroll 1
    for (int t = 0; t < NT32; ++t) {
        f16x8 a[4];
#pragma unroll
        for (int m = 0; m < 4; ++m) { a[m] = *(const f16x8*)ap[m]; ap[m] += 1024; }
        if (t + 1 < NT32) STAGEB(nx);
        f16x8 b[4];
#pragma unroll
        for (int n = 0; n < 4; ++n) b[n] = *(const f16x8*)(cb + offB[n]);
        __builtin_amdgcn_s_setprio(1);
#pragma unroll
        for (int m = 0; m < 4; ++m)
#pragma unroll
            for (int n = 0; n < 4; ++n)
                acc[m][n] = __builtin_amdgcn_mfma_f32_16x16x32_f16(a[m], b[n], acc[m][n], 0, 0, 0);
        __builtin_amdgcn_s_setprio(0);
        __syncthreads();     // publishes B stage, retires reads (4-wave domain)
        char* tmp = cb; cb = nx; nx = tmp;
    }
#undef STAGEB

    // ---- fused epilogue (128 rows x 64 cols, verified pattern) ----
    const bool last = (stepi == 15);
    f16* Cand = (f16*)lds;
    f16* Gate = (f16*)(lds + 18432);           // 128*72*2 = 18432
#pragma unroll
    for (int m = 0; m < 4; ++m)
#pragma unroll
        for (int n = 0; n < 2; ++n)
#pragma unroll
            for (int r4 = 0; r4 < 4; ++r4) {
                int row = wr * 64 + m * 16 + l4 * 4 + r4;
                int cc = wc * 32 + n * 16 + l15;
                Cand[row * EPW + cc] = (f16)acc[m][n][r4];
                Gate[row * EPW + cc] = (f16)acc[m][n + 2][r4];
            }
    __syncthreads();
    {
        const int g = tid & 7;
        const int rb = tid >> 3;                       // 0..31
        const int dl = g * 8;
        const int d = tb * 64 + dl;
        float4 byc0 = *(const float4*)(by + d);
        float4 byc1 = *(const float4*)(by + d + 4);
        float4 byg0 = *(const float4*)(by + H + d);
        float4 byg1 = *(const float4*)(by + H + d + 4);
#pragma unroll
        for (int p = 0; p < 4; ++p) {
            int row = p * 32 + rb;                     // 0..127
            int grow = bm * 128 + row;
            int s = grow & (SEQ - 1);
            size_t fa = frag_off(grow, d);
            f16x8 c8 = *(const f16x8*)(Cand + row * EPW + dl);
            f16x8 g8 = *(const f16x8*)(Gate + row * EPW + dl);
            f16x8 p8 = {};
            if (s >= 15 - stepi)
                p8 = *(const f16x8*)(P16 + (size_t)(grow + stepi - 15) * H + d);
            f16x8 s8 = *(const f16x8*)(A + fa);            // old state (fragment)
            f16x8 o8; float ov[8];
#pragma unroll
            for (int j = 0; j < 8; ++j) {
                float byc = (j < 4) ? ((const float*)&byc0)[j] : ((const float*)&byc1)[j - 4];
                float byg = (j < 4) ? ((const float*)&byg0)[j] : ((const float*)&byg1)[j - 4];
                float cand = (float)c8[j] + byc;
                float gg = gate_fn((float)g8[j] + byg);
                float v = fmaxf(gg * ((float)p8[j] + cand) + (1.f - gg) * (float)s8[j], 0.f);
                o8[j] = (f16)v; ov[j] = v;
            }
            if (!last) {
                *(f16x8*)(Snext + fa) = o8;                // fragment layout
            } else {
                *(float4*)(Out + (size_t)grow * H + d) = make_float4(ov[0], ov[1], ov[2], ov[3]);
                *(float4*)(Out + (size_t)grow * H + d + 4) = make_float4(ov[4], ov[5], ov[6], ov[7]);
            }
        }
    }
}

extern "C" void kernel_launch(void* const* d_in, const int* in_sizes, int n_in,
                              void* d_out, int out_size, void* d_ws, size_t ws_size,
                              hipStream_t stream) {
    (void)in_sizes; (void)n_in; (void)out_size; (void)ws_size;
    const float* x  = (const float*)d_in[0];
    const float* Wx = (const float*)d_in[1];
    const float* Wy = (const float*)d_in[2];
    const float* by = (const float*)d_in[3];
    float* out = (float*)d_out;

    char* ws = (char*)d_ws;
    const size_t MB = 1024ull * 1024ull;
    f16* st16a = (f16*)(ws);             // 32 MiB: row-major x_f16 for proj, then state ping (fragment)
    f16* st16b = (f16*)(ws + 32 * MB);   // 32 MiB: state pong (fragment)
    f16* P16   = (f16*)(ws + 64 * MB);   // 32 MiB: projection, fp16 row-major
    f16* WxT   = (f16*)(ws + 96 * MB);   // 2 MiB (row-major, proj B)
    f16* WyT   = (f16*)(ws + 98 * MB);   // 4 MiB (row-major, step B)

    hipLaunchKernelGGL(k_f32_to_f16, dim3(MROWS * H / 8 / 256), dim3(256), 0, stream, x, st16a);
    hipLaunchKernelGGL(k_transpose_f16, dim3(H / 32, H / 32), dim3(32, 8), 0, stream, Wx, WxT, H, H);
    hipLaunchKernelGGL(k_transpose_f16, dim3(2 * H / 32, H / 32), dim3(32, 8), 0, stream, Wy, WyT, H, 2 * H);
    hipLaunchKernelGGL(k_proj_gemm, dim3(MROWS / 128, H / 128), dim3(256), 0, stream, st16a, WxT, P16);
    hipLaunchKernelGGL(k_step0, dim3(MROWS * H / 8 / 256), dim3(256), 0, stream, P16, by, st16b);

    f16* bufs[2] = {st16a, st16b};
    for (int i = 1; i <= 15; ++i) {
        const f16* cur = bufs[i & 1];
        f16* nxt = bufs[(i + 1) & 1];
        hipLaunchKernelGGL(k_step_gemm, dim3(MROWS / 128 * 16), dim3(256), 0, stream,
                           cur, WyT, P16, by, out, nxt, i);
    }
}

// Round 24
// 1226.963 us; speedup vs baseline: 1.1037x; 1.1037x over previous
//
#include <hip/hip_runtime.h>

#define H 1024
#define SEQ 2048
#define MROWS 16384           // 8 * 2048
#define KD 1024               // GEMM K dim
#define NT32 32               // K-tiles of 32
#define EPW 72                // epilogue LDS stride (f16)

typedef _Float16 f16;
typedef _Float16 f16x8 __attribute__((ext_vector_type(8)));
typedef float f32x4 __attribute__((ext_vector_type(4)));

__device__ __forceinline__ float gate_fn(float x) {
    float s = 1.0f / (1.0f + __expf(-x));
    return fminf(fmaxf(1.2f * s - 0.1f, 0.0f), 1.0f);
}

// fragment-major state layout: element (row,k) ->
//   S'[row>>4][k>>5][lane][j],  lane=(row&15)|(((k>>3)&3)<<4), j=k&7
// flat elems: ((row>>4)*32 + (k>>5))*512 + lane*8 + j
// A wave's MFMA A-fragment (16 rows x 32 k) = ONE contiguous 1KB block.
__device__ __forceinline__ size_t frag_off(int row, int k) {
    return ((size_t)((row >> 4) * 32 + (k >> 5))) * 512
         + (size_t)((((row & 15) | (((k >> 3) & 3) << 4)) << 3) + (k & 7));
}

__device__ __forceinline__ void gload_lds16(const void* g, void* lds) {
    __builtin_amdgcn_global_load_lds(
        (const __attribute__((address_space(1))) unsigned int*)g,
        (__attribute__((address_space(3))) unsigned int*)lds, 16, 0, 0);
}

// ---------------- fp32 -> fp16 convert (row-major, for proj A) ----------------
__global__ void k_f32_to_f16(const float* __restrict__ in, f16* __restrict__ out) {
    size_t i = ((size_t)blockIdx.x * blockDim.x + threadIdx.x) * 8;
    float4 v0 = *(const float4*)(in + i);
    float4 v1 = *(const float4*)(in + i + 4);
    f16x8 o;
    o[0] = (f16)v0.x; o[1] = (f16)v0.y; o[2] = (f16)v0.z; o[3] = (f16)v0.w;
    o[4] = (f16)v1.x; o[5] = (f16)v1.y; o[6] = (f16)v1.z; o[7] = (f16)v1.w;
    *(f16x8*)(out + i) = o;
}

// ---------------- transpose + convert: WT[n][k] = (f16)W[k][n] ----------------
__global__ void k_transpose_f16(const float* __restrict__ Wsrc, f16* __restrict__ WT,
                                int K, int N) {
    __shared__ float tile[32][33];
    int n0 = blockIdx.x * 32, k0 = blockIdx.y * 32;
    for (int i = threadIdx.y; i < 32; i += 8)
        tile[i][threadIdx.x] = Wsrc[(size_t)(k0 + i) * N + n0 + threadIdx.x];
    __syncthreads();
    for (int i = threadIdx.y; i < 32; i += 8)
        WT[(size_t)(n0 + i) * K + k0 + threadIdx.x] = (f16)tile[threadIdx.x][i];
}

// ---------------- proj GEMM (128x128, row-major A) ----------------
__global__ __launch_bounds__(256) void k_proj_gemm(const f16* __restrict__ A,
                                                   const f16* __restrict__ BT,
                                                   f16* __restrict__ P16) {
    __shared__ alignas(16) f16 Alds[128 * 32];
    __shared__ alignas(16) f16 Blds[128 * 32];
    const int tid = threadIdx.x;
    const int lane = tid & 63, wid = tid >> 6;
    const int l15 = lane & 15, l4 = lane >> 4;
    const int bm = blockIdx.x, bn = blockIdx.y;

    const f16* gA[2]; const f16* gB[2];
    char* ldsA[2]; char* ldsB[2];
#pragma unroll
    for (int it = 0; it < 2; ++it) {
        int c = it * 4 + wid;
        int row = c * 16 + (lane >> 2);
        int kch = (lane & 3) ^ ((row >> 1) & 3);
        gA[it] = A + (size_t)(bm * 128 + row) * KD + kch * 8;
        gB[it] = BT + (size_t)(bn * 128 + row) * KD + kch * 8;
        ldsA[it] = (char*)Alds + c * 1024;
        ldsB[it] = (char*)Blds + c * 1024;
    }

    int offA[2], offB[8];
#pragma unroll
    for (int m = 0; m < 2; ++m) {
        int row = wid * 32 + m * 16 + l15;
        offA[m] = row * 64 + ((l4 ^ ((row >> 1) & 3)) << 4);
    }
#pragma unroll
    for (int n = 0; n < 8; ++n) {
        int row = n * 16 + l15;
        offB[n] = row * 64 + ((l4 ^ ((row >> 1) & 3)) << 4);
    }

    f32x4 acc[2][8] = {};

    for (int kt = 0; kt < KD / 32; ++kt) {
        __syncthreads();
#pragma unroll
        for (int it = 0; it < 2; ++it) {
            gload_lds16(gA[it], ldsA[it]);
            gload_lds16(gB[it], ldsB[it]);
            gA[it] += 32; gB[it] += 32;
        }
        __syncthreads();
        f16x8 a[2], b[8];
#pragma unroll
        for (int m = 0; m < 2; ++m) a[m] = *(const f16x8*)((const char*)Alds + offA[m]);
#pragma unroll
        for (int n = 0; n < 8; ++n) b[n] = *(const f16x8*)((const char*)Blds + offB[n]);
#pragma unroll
        for (int n = 0; n < 8; ++n)
#pragma unroll
            for (int m = 0; m < 2; ++m)
                acc[m][n] = __builtin_amdgcn_mfma_f32_16x16x32_f16(a[m], b[n], acc[m][n], 0, 0, 0);
    }

#pragma unroll
    for (int m = 0; m < 2; ++m)
#pragma unroll
        for (int n = 0; n < 8; ++n) {
            int col = bn * 128 + n * 16 + l15;
#pragma unroll
            for (int r = 0; r < 4; ++r) {
                int row = bm * 128 + wid * 32 + m * 16 + l4 * 4 + r;
                P16[(size_t)row * H + col] = (f16)acc[m][n][r];
            }
        }
}

// ---------------- step 0 (state==0): writes S16 in FRAGMENT layout ----------------
__global__ void k_step0(const f16* __restrict__ P16, const float* __restrict__ by,
                        f16* __restrict__ S16) {
    size_t idx = ((size_t)blockIdx.x * blockDim.x + threadIdx.x) * 8;
    int row = (int)(idx >> 10);
    int d = (int)(idx & 1023);
    int s = row & (SEQ - 1);
    f16x8 p = {};
    if (s >= 15) p = *(const f16x8*)(P16 + (size_t)(row - 15) * H + d);
    float4 byc0 = *(const float4*)(by + d);
    float4 byc1 = *(const float4*)(by + d + 4);
    float4 byg0 = *(const float4*)(by + H + d);
    float4 byg1 = *(const float4*)(by + H + d + 4);
    f16x8 sv;
#pragma unroll
    for (int j = 0; j < 8; ++j) {
        float byc = (j < 4) ? ((const float*)&byc0)[j] : ((const float*)&byc1)[j - 4];
        float byg = (j < 4) ? ((const float*)&byg0)[j] : ((const float*)&byg1)[j - 4];
        float g = gate_fn(byg);
        float v = fmaxf(g * ((float)p[j] + byc), 0.f);
        sv[j] = (f16)v;
    }
    *(f16x8*)(S16 + frag_off(row, d)) = sv;
}

// ---------------- step GEMM: fragment-major A direct-to-reg, B via LDS ----------------
// A = state_f16 FRAGMENT layout; BT = WyT [2H][K] row-major. Block (bm,tb):
// rows bm*256..+256, cand cols tb*64..+64 + gates. 8 waves, wave 64x64,
// acc[4][4]=64 AGPR. A fragment = ONE coalesced 1KB global_load_dwordx4 per
// m-tile per K-tile (lane*16B contiguous) -- no LDS, no fragmentation, L2-hot.
// B via verified 1-barrier LDS dbuf (2x8KB). 120 unified regs -> 4 waves/SIMD,
// 2 blocks/CU (73728B LDS). Measured best: 81.6-82.0 us/step, ~848 TF effective,
// 93% of the plain-HIP simple-structure ceiling (m97/m103: 874-912 TF).
// Verified local optimum: barrier-domain size (R5-R10 fewer / R23 more both
// lose), tile shape (4 variants), MFMA shape (R18), operand placement
// (R16/R17), schedule family (7 variants), pipeline depth (R13 spills).
__global__ __launch_bounds__(512, 4) void k_step_gemm(const f16* __restrict__ A,
                                                      const f16* __restrict__ BT,
                                                      const f16* __restrict__ P16,
                                                      const float* __restrict__ by,
                                                      float* __restrict__ Out,
                                                      f16* __restrict__ Snext,
                                                      int stepi) {
    __shared__ alignas(16) char lds[73728];    // B dbuf 2x8KB; epilogue 2x36KB
    const int tid = threadIdx.x;
    const int lane = tid & 63, w = tid >> 6;
    const int l15 = lane & 15, l4 = lane >> 4;
    const int wr = w >> 1, wc = w & 1;

    // bijective XCD swizzle: 1024 wgs, 128/XCD, tb fastest (A-panel L2 reuse)
    const int orig = blockIdx.x;
    const int wg = (orig & 7) * 128 + (orig >> 3);
    const int bm = wg >> 4, tb = wg & 15;

    // B staging source (pre-swizzled k-slot): thread t -> B-tile row t>>2, slot t&3
    const int rB = tid >> 2;                                 // 0..127
    const int rowB = ((rB & 32) ? H : 0) + tb * 64 + ((rB >> 6) << 5) + (rB & 31);
    const int slotB = (tid & 3) ^ ((rB >> 1) & 3);
    const char* pB = (const char*)BT + ((size_t)rowB * KD + slotB * 8) * 2;

    // A fragment pointers: m-tile m -> 1KB block ((R>>4)*32 + kt)*1024B, lane*16B
    const char* ap[4];
#pragma unroll
    for (int m = 0; m < 4; ++m) {
        int r16 = bm * 16 + wr * 4 + m;        // (row>>4) index
        ap[m] = (const char*)A + ((size_t)r16 * 32) * 1024 + lane * 16;
    }

#define STAGEB(bp) do { gload_lds16(pB, (bp) + tid * 16); pB += 64; } while (0)

    const int sx = (l4 ^ ((l15 >> 1) & 3)) << 4;
    int offB[4];
#pragma unroll
    for (int n = 0; n < 4; ++n) offB[n] = (wc * 64 + n * 16 + l15) * 64 + sx;

    f32x4 acc[4][4] = {};

    char* const buf0 = lds;
    char* const buf1 = lds + 8192;
    char* cb = buf0;
    char* nx = buf1;

    STAGEB(buf0);
    __syncthreads();

#pragma unroll 1
    for (int t = 0; t < NT32; ++t) {
        // A fragment loads FIRST (global, coalesced 1KB; latency overlaps b reads)
        f16x8 a[4];
#pragma unroll
        for (int m = 0; m < 4; ++m) { a[m] = *(const f16x8*)ap[m]; ap[m] += 1024; }
        if (t + 1 < NT32) STAGEB(nx);
        f16x8 b[4];
#pragma unroll
        for (int n = 0; n < 4; ++n) b[n] = *(const f16x8*)(cb + offB[n]);
        __builtin_amdgcn_s_setprio(1);
#pragma unroll
        for (int m = 0; m < 4; ++m)
#pragma unroll
            for (int n = 0; n < 4; ++n)
                acc[m][n] = __builtin_amdgcn_mfma_f32_16x16x32_f16(a[m], b[n], acc[m][n], 0, 0, 0);
        __builtin_amdgcn_s_setprio(0);
        __syncthreads();     // publishes B stage, retires reads
        char* tmp = cb; cb = nx; nx = tmp;
    }
#undef STAGEB

    // ---- fused epilogue (single 64-col round, verified pattern) ----
    const bool last = (stepi == 15);
    f16* Cand = (f16*)lds;
    f16* Gate = (f16*)(lds + 36864);
#pragma unroll
    for (int m = 0; m < 4; ++m)
#pragma unroll
        for (int n = 0; n < 2; ++n)
#pragma unroll
            for (int r4 = 0; r4 < 4; ++r4) {
                int row = wr * 64 + m * 16 + l4 * 4 + r4;
                int cc = wc * 32 + n * 16 + l15;
                Cand[row * EPW + cc] = (f16)acc[m][n][r4];
                Gate[row * EPW + cc] = (f16)acc[m][n + 2][r4];
            }
    __syncthreads();
    {
        const int g = tid & 7;
        const int rb = tid >> 3;                       // 0..63
        const int dl = g * 8;
        const int d = tb * 64 + dl;
        float4 byc0 = *(const float4*)(by + d);
        float4 byc1 = *(const float4*)(by + d + 4);
        float4 byg0 = *(const float4*)(by + H + d);
        float4 byg1 = *(const float4*)(by + H + d + 4);
#pragma unroll
        for (int p = 0; p < 4; ++p) {
            int row = p * 64 + rb;
            int grow = bm * 256 + row;
            int s = grow & (SEQ - 1);
            size_t fa = frag_off(grow, d);
            f16x8 c8 = *(const f16x8*)(Cand + row * EPW + dl);
            f16x8 g8 = *(const f16x8*)(Gate + row * EPW + dl);
            f16x8 p8 = {};
            if (s >= 15 - stepi)
                p8 = *(const f16x8*)(P16 + (size_t)(grow + stepi - 15) * H + d);
            f16x8 s8 = *(const f16x8*)(A + fa);            // old state (fragment)
            f16x8 o8; float ov[8];
#pragma unroll
            for (int j = 0; j < 8; ++j) {
                float byc = (j < 4) ? ((const float*)&byc0)[j] : ((const float*)&byc1)[j - 4];
                float byg = (j < 4) ? ((const float*)&byg0)[j] : ((const float*)&byg1)[j - 4];
                float cand = (float)c8[j] + byc;
                float gg = gate_fn((float)g8[j] + byg);
                float v = fmaxf(gg * ((float)p8[j] + cand) + (1.f - gg) * (float)s8[j], 0.f);
                o8[j] = (f16)v; ov[j] = v;
            }
            if (!last) {
                *(f16x8*)(Snext + fa) = o8;                // fragment layout
            } else {
                *(float4*)(Out + (size_t)grow * H + d) = make_float4(ov[0], ov[1], ov[2], ov[3]);
                *(float4*)(Out + (size_t)grow * H + d + 4) = make_float4(ov[4], ov[5], ov[6], ov[7]);
            }
        }
    }
}

extern "C" void kernel_launch(void* const* d_in, const int* in_sizes, int n_in,
                              void* d_out, int out_size, void* d_ws, size_t ws_size,
                              hipStream_t stream) {
    (void)in_sizes; (void)n_in; (void)out_size; (void)ws_size;
    const float* x  = (const float*)d_in[0];
    const float* Wx = (const float*)d_in[1];
    const float* Wy = (const float*)d_in[2];
    const float* by = (const float*)d_in[3];
    float* out = (float*)d_out;

    char* ws = (char*)d_ws;
    const size_t MB = 1024ull * 1024ull;
    f16* st16a = (f16*)(ws);             // 32 MiB: row-major x_f16 for proj, then state ping (fragment)
    f16* st16b = (f16*)(ws + 32 * MB);   // 32 MiB: state pong (fragment)
    f16* P16   = (f16*)(ws + 64 * MB);   // 32 MiB: projection, fp16 row-major
    f16* WxT   = (f16*)(ws + 96 * MB);   // 2 MiB (row-major, proj B)
    f16* WyT   = (f16*)(ws + 98 * MB);   // 4 MiB (row-major, step B)

    hipLaunchKernelGGL(k_f32_to_f16, dim3(MROWS * H / 8 / 256), dim3(256), 0, stream, x, st16a);
    hipLaunchKernelGGL(k_transpose_f16, dim3(H / 32, H / 32), dim3(32, 8), 0, stream, Wx, WxT, H, H);
    hipLaunchKernelGGL(k_transpose_f16, dim3(2 * H / 32, H / 32), dim3(32, 8), 0, stream, Wy, WyT, H, 2 * H);
    hipLaunchKernelGGL(k_proj_gemm, dim3(MROWS / 128, H / 128), dim3(256), 0, stream, st16a, WxT, P16);
    hipLaunchKernelGGL(k_step0, dim3(MROWS * H / 8 / 256), dim3(256), 0, stream, P16, by, st16b);

    f16* bufs[2] = {st16a, st16b};
    for (int i = 1; i <= 15; ++i) {
        const f16* cur = bufs[i & 1];
        f16* nxt = bufs[(i + 1) & 1];
        hipLaunchKernelGGL(k_step_gemm, dim3(MROWS / 256 * 16), dim3(512), 0, stream,
                           cur, WyT, P16, by, out, nxt, i);
    }
}

// Round 25
// 1222.875 us; speedup vs baseline: 1.1074x; 1.0033x over previous
//
#include <hip/hip_runtime.h>

#define H 1024
#define SEQ 2048
#define MROWS 16384           // 8 * 2048
#define KD 1024               // GEMM K dim
#define NT32 32               // K-tiles of 32
#define EPW 72                // epilogue LDS stride (f16)

typedef _Float16 f16;
typedef _Float16 f16x8 __attribute__((ext_vector_type(8)));
typedef float f32x4 __attribute__((ext_vector_type(4)));

__device__ __forceinline__ float gate_fn(float x) {
    float s = 1.0f / (1.0f + __expf(-x));
    return fminf(fmaxf(1.2f * s - 0.1f, 0.0f), 1.0f);
}

// fragment-major state layout: element (row,k) ->
//   S'[row>>4][k>>5][lane][j],  lane=(row&15)|(((k>>3)&3)<<4), j=k&7
// flat elems: ((row>>4)*32 + (k>>5))*512 + lane*8 + j
// A wave's MFMA A-fragment (16 rows x 32 k) = ONE contiguous 1KB block.
__device__ __forceinline__ size_t frag_off(int row, int k) {
    return ((size_t)((row >> 4) * 32 + (k >> 5))) * 512
         + (size_t)((((row & 15) | (((k >> 3) & 3) << 4)) << 3) + (k & 7));
}

__device__ __forceinline__ void gload_lds16(const void* g, void* lds) {
    __builtin_amdgcn_global_load_lds(
        (const __attribute__((address_space(1))) unsigned int*)g,
        (__attribute__((address_space(3))) unsigned int*)lds, 16, 0, 0);
}

// ---------------- fp32 -> fp16 convert (row-major, for proj A) ----------------
__global__ void k_f32_to_f16(const float* __restrict__ in, f16* __restrict__ out) {
    size_t i = ((size_t)blockIdx.x * blockDim.x + threadIdx.x) * 8;
    float4 v0 = *(const float4*)(in + i);
    float4 v1 = *(const float4*)(in + i + 4);
    f16x8 o;
    o[0] = (f16)v0.x; o[1] = (f16)v0.y; o[2] = (f16)v0.z; o[3] = (f16)v0.w;
    o[4] = (f16)v1.x; o[5] = (f16)v1.y; o[6] = (f16)v1.z; o[7] = (f16)v1.w;
    *(f16x8*)(out + i) = o;
}

// ---------------- transpose + convert: WT[n][k] = (f16)W[k][n] ----------------
__global__ void k_transpose_f16(const float* __restrict__ Wsrc, f16* __restrict__ WT,
                                int K, int N) {
    __shared__ float tile[32][33];
    int n0 = blockIdx.x * 32, k0 = blockIdx.y * 32;
    for (int i = threadIdx.y; i < 32; i += 8)
        tile[i][threadIdx.x] = Wsrc[(size_t)(k0 + i) * N + n0 + threadIdx.x];
    __syncthreads();
    for (int i = threadIdx.y; i < 32; i += 8)
        WT[(size_t)(n0 + i) * K + k0 + threadIdx.x] = (f16)tile[threadIdx.x][i];
}

// ---------------- proj GEMM (128x128, row-major A) ----------------
__global__ __launch_bounds__(256) void k_proj_gemm(const f16* __restrict__ A,
                                                   const f16* __restrict__ BT,
                                                   f16* __restrict__ P16) {
    __shared__ alignas(16) f16 Alds[128 * 32];
    __shared__ alignas(16) f16 Blds[128 * 32];
    const int tid = threadIdx.x;
    const int lane = tid & 63, wid = tid >> 6;
    const int l15 = lane & 15, l4 = lane >> 4;
    const int bm = blockIdx.x, bn = blockIdx.y;

    const f16* gA[2]; const f16* gB[2];
    char* ldsA[2]; char* ldsB[2];
#pragma unroll
    for (int it = 0; it < 2; ++it) {
        int c = it * 4 + wid;
        int row = c * 16 + (lane >> 2);
        int kch = (lane & 3) ^ ((row >> 1) & 3);
        gA[it] = A + (size_t)(bm * 128 + row) * KD + kch * 8;
        gB[it] = BT + (size_t)(bn * 128 + row) * KD + kch * 8;
        ldsA[it] = (char*)Alds + c * 1024;
        ldsB[it] = (char*)Blds + c * 1024;
    }

    int offA[2], offB[8];
#pragma unroll
    for (int m = 0; m < 2; ++m) {
        int row = wid * 32 + m * 16 + l15;
        offA[m] = row * 64 + ((l4 ^ ((row >> 1) & 3)) << 4);
    }
#pragma unroll
    for (int n = 0; n < 8; ++n) {
        int row = n * 16 + l15;
        offB[n] = row * 64 + ((l4 ^ ((row >> 1) & 3)) << 4);
    }

    f32x4 acc[2][8] = {};

    for (int kt = 0; kt < KD / 32; ++kt) {
        __syncthreads();
#pragma unroll
        for (int it = 0; it < 2; ++it) {
            gload_lds16(gA[it], ldsA[it]);
            gload_lds16(gB[it], ldsB[it]);
            gA[it] += 32; gB[it] += 32;
        }
        __syncthreads();
        f16x8 a[2], b[8];
#pragma unroll
        for (int m = 0; m < 2; ++m) a[m] = *(const f16x8*)((const char*)Alds + offA[m]);
#pragma unroll
        for (int n = 0; n < 8; ++n) b[n] = *(const f16x8*)((const char*)Blds + offB[n]);
#pragma unroll
        for (int n = 0; n < 8; ++n)
#pragma unroll
            for (int m = 0; m < 2; ++m)
                acc[m][n] = __builtin_amdgcn_mfma_f32_16x16x32_f16(a[m], b[n], acc[m][n], 0, 0, 0);
    }

#pragma unroll
    for (int m = 0; m < 2; ++m)
#pragma unroll
        for (int n = 0; n < 8; ++n) {
            int col = bn * 128 + n * 16 + l15;
#pragma unroll
            for (int r = 0; r < 4; ++r) {
                int row = bm * 128 + wid * 32 + m * 16 + l4 * 4 + r;
                P16[(size_t)row * H + col] = (f16)acc[m][n][r];
            }
        }
}

// ---------------- step 0 (state==0): writes S16 in FRAGMENT layout ----------------
__global__ void k_step0(const f16* __restrict__ P16, const float* __restrict__ by,
                        f16* __restrict__ S16) {
    size_t idx = ((size_t)blockIdx.x * blockDim.x + threadIdx.x) * 8;
    int row = (int)(idx >> 10);
    int d = (int)(idx & 1023);
    int s = row & (SEQ - 1);
    f16x8 p = {};
    if (s >= 15) p = *(const f16x8*)(P16 + (size_t)(row - 15) * H + d);
    float4 byc0 = *(const float4*)(by + d);
    float4 byc1 = *(const float4*)(by + d + 4);
    float4 byg0 = *(const float4*)(by + H + d);
    float4 byg1 = *(const float4*)(by + H + d + 4);
    f16x8 sv;
#pragma unroll
    for (int j = 0; j < 8; ++j) {
        float byc = (j < 4) ? ((const float*)&byc0)[j] : ((const float*)&byc1)[j - 4];
        float byg = (j < 4) ? ((const float*)&byg0)[j] : ((const float*)&byg1)[j - 4];
        float g = gate_fn(byg);
        float v = fmaxf(g * ((float)p[j] + byc), 0.f);
        sv[j] = (f16)v;
    }
    *(f16x8*)(S16 + frag_off(row, d)) = sv;
}

// ---------------- step GEMM: fragment-major A direct-to-reg, B via LDS ----------------
// A = state_f16 FRAGMENT layout; BT = WyT [2H][K] row-major. Block (bm,tb):
// rows bm*256..+256, cand cols tb*64..+64 + gates. 8 waves, wave 64x64,
// acc[4][4]=64 AGPR. A fragment = ONE coalesced 1KB global_load_dwordx4 per
// m-tile per K-tile (lane*16B contiguous) -- no LDS, no fragmentation, L2-hot.
// B via verified 1-barrier LDS dbuf (2x8KB). 120 unified regs -> 4 waves/SIMD,
// 2 blocks/CU (73728B LDS). Measured best: 81.2-82.0 us/step, ~848 TF effective,
// 93% of the plain-HIP simple-structure ceiling (m97/m103: 874-912 TF).
// Verified local optimum along all probed axes: barrier-domain size (R5-R10
// fewer / R23 more both lose), tile shape, MFMA shape (R18), operand placement
// (R16/R17), schedule family (7 variants), pipeline depth (R13 spills).
__global__ __launch_bounds__(512, 4) void k_step_gemm(const f16* __restrict__ A,
                                                      const f16* __restrict__ BT,
                                                      const f16* __restrict__ P16,
                                                      const float* __restrict__ by,
                                                      float* __restrict__ Out,
                                                      f16* __restrict__ Snext,
                                                      int stepi) {
    __shared__ alignas(16) char lds[73728];    // B dbuf 2x8KB; epilogue 2x36KB
    const int tid = threadIdx.x;
    const int lane = tid & 63, w = tid >> 6;
    const int l15 = lane & 15, l4 = lane >> 4;
    const int wr = w >> 1, wc = w & 1;

    // bijective XCD swizzle: 1024 wgs, 128/XCD, tb fastest (A-panel L2 reuse)
    const int orig = blockIdx.x;
    const int wg = (orig & 7) * 128 + (orig >> 3);
    const int bm = wg >> 4, tb = wg & 15;

    // B staging source (pre-swizzled k-slot): thread t -> B-tile row t>>2, slot t&3
    const int rB = tid >> 2;                                 // 0..127
    const int rowB = ((rB & 32) ? H : 0) + tb * 64 + ((rB >> 6) << 5) + (rB & 31);
    const int slotB = (tid & 3) ^ ((rB >> 1) & 3);
    const char* pB = (const char*)BT + ((size_t)rowB * KD + slotB * 8) * 2;

    // A fragment pointers: m-tile m -> 1KB block ((R>>4)*32 + kt)*1024B, lane*16B
    const char* ap[4];
#pragma unroll
    for (int m = 0; m < 4; ++m) {
        int r16 = bm * 16 + wr * 4 + m;        // (row>>4) index
        ap[m] = (const char*)A + ((size_t)r16 * 32) * 1024 + lane * 16;
    }

#define STAGEB(bp) do { gload_lds16(pB, (bp) + tid * 16); pB += 64; } while (0)

    const int sx = (l4 ^ ((l15 >> 1) & 3)) << 4;
    int offB[4];
#pragma unroll
    for (int n = 0; n < 4; ++n) offB[n] = (wc * 64 + n * 16 + l15) * 64 + sx;

    f32x4 acc[4][4] = {};

    char* const buf0 = lds;
    char* const buf1 = lds + 8192;
    char* cb = buf0;
    char* nx = buf1;

    STAGEB(buf0);
    __syncthreads();

#pragma unroll 1
    for (int t = 0; t < NT32; ++t) {
        // A fragment loads FIRST (global, coalesced 1KB; latency overlaps b reads)
        f16x8 a[4];
#pragma unroll
        for (int m = 0; m < 4; ++m) { a[m] = *(const f16x8*)ap[m]; ap[m] += 1024; }
        if (t + 1 < NT32) STAGEB(nx);
        f16x8 b[4];
#pragma unroll
        for (int n = 0; n < 4; ++n) b[n] = *(const f16x8*)(cb + offB[n]);
        __builtin_amdgcn_s_setprio(1);
#pragma unroll
        for (int m = 0; m < 4; ++m)
#pragma unroll
            for (int n = 0; n < 4; ++n)
                acc[m][n] = __builtin_amdgcn_mfma_f32_16x16x32_f16(a[m], b[n], acc[m][n], 0, 0, 0);
        __builtin_amdgcn_s_setprio(0);
        __syncthreads();     // publishes B stage, retires reads
        char* tmp = cb; cb = nx; nx = tmp;
    }
#undef STAGEB

    // ---- fused epilogue (single 64-col round, verified pattern) ----
    const bool last = (stepi == 15);
    f16* Cand = (f16*)lds;
    f16* Gate = (f16*)(lds + 36864);
#pragma unroll
    for (int m = 0; m < 4; ++m)
#pragma unroll
        for (int n = 0; n < 2; ++n)
#pragma unroll
            for (int r4 = 0; r4 < 4; ++r4) {
                int row = wr * 64 + m * 16 + l4 * 4 + r4;
                int cc = wc * 32 + n * 16 + l15;
                Cand[row * EPW + cc] = (f16)acc[m][n][r4];
                Gate[row * EPW + cc] = (f16)acc[m][n + 2][r4];
            }
    __syncthreads();
    {
        const int g = tid & 7;
        const int rb = tid >> 3;                       // 0..63
        const int dl = g * 8;
        const int d = tb * 64 + dl;
        float4 byc0 = *(const float4*)(by + d);
        float4 byc1 = *(const float4*)(by + d + 4);
        float4 byg0 = *(const float4*)(by + H + d);
        float4 byg1 = *(const float4*)(by + H + d + 4);
#pragma unroll
        for (int p = 0; p < 4; ++p) {
            int row = p * 64 + rb;
            int grow = bm * 256 + row;
            int s = grow & (SEQ - 1);
            size_t fa = frag_off(grow, d);
            f16x8 c8 = *(const f16x8*)(Cand + row * EPW + dl);
            f16x8 g8 = *(const f16x8*)(Gate + row * EPW + dl);
            f16x8 p8 = {};
            if (s >= 15 - stepi)
                p8 = *(const f16x8*)(P16 + (size_t)(grow + stepi - 15) * H + d);
            f16x8 s8 = *(const f16x8*)(A + fa);            // old state (fragment)
            f16x8 o8; float ov[8];
#pragma unroll
            for (int j = 0; j < 8; ++j) {
                float byc = (j < 4) ? ((const float*)&byc0)[j] : ((const float*)&byc1)[j - 4];
                float byg = (j < 4) ? ((const float*)&byg0)[j] : ((const float*)&byg1)[j - 4];
                float cand = (float)c8[j] + byc;
                float gg = gate_fn((float)g8[j] + byg);
                float v = fmaxf(gg * ((float)p8[j] + cand) + (1.f - gg) * (float)s8[j], 0.f);
                o8[j] = (f16)v; ov[j] = v;
            }
            if (!last) {
                *(f16x8*)(Snext + fa) = o8;                // fragment layout
            } else {
                *(float4*)(Out + (size_t)grow * H + d) = make_float4(ov[0], ov[1], ov[2], ov[3]);
                *(float4*)(Out + (size_t)grow * H + d + 4) = make_float4(ov[4], ov[5], ov[6], ov[7]);
            }
        }
    }
}

extern "C" void kernel_launch(void* const* d_in, const int* in_sizes, int n_in,
                              void* d_out, int out_size, void* d_ws, size_t ws_size,
                              hipStream_t stream) {
    (void)in_sizes; (void)n_in; (void)out_size; (void)ws_size;
    const float* x  = (const float*)d_in[0];
    const float* Wx = (const float*)d_in[1];
    const float* Wy = (const float*)d_in[2];
    const float* by = (const float*)d_in[3];
    float* out = (float*)d_out;

    char* ws = (char*)d_ws;
    const size_t MB = 1024ull * 1024ull;
    f16* st16a = (f16*)(ws);             // 32 MiB: row-major x_f16 for proj, then state ping (fragment)
    f16* st16b = (f16*)(ws + 32 * MB);   // 32 MiB: state pong (fragment)
    f16* P16   = (f16*)(ws + 64 * MB);   // 32 MiB: projection, fp16 row-major
    f16* WxT   = (f16*)(ws + 96 * MB);   // 2 MiB (row-major, proj B)
    f16* WyT   = (f16*)(ws + 98 * MB);   // 4 MiB (row-major, step B)

    hipLaunchKernelGGL(k_f32_to_f16, dim3(MROWS * H / 8 / 256), dim3(256), 0, stream, x, st16a);
    hipLaunchKernelGGL(k_transpose_f16, dim3(H / 32, H / 32), dim3(32, 8), 0, stream, Wx, WxT, H, H);
    hipLaunchKernelGGL(k_transpose_f16, dim3(2 * H / 32, H / 32), dim3(32, 8), 0, stream, Wy, WyT, H, 2 * H);
    hipLaunchKernelGGL(k_proj_gemm, dim3(MROWS / 128, H / 128), dim3(256), 0, stream, st16a, WxT, P16);
    hipLaunchKernelGGL(k_step0, dim3(MROWS * H / 8 / 256), dim3(256), 0, stream, P16, by, st16b);

    f16* bufs[2] = {st16a, st16b};
    for (int i = 1; i <= 15; ++i) {
        const f16* cur = bufs[i & 1];
        f16* nxt = bufs[(i + 1) & 1];
        hipLaunchKernelGGL(k_step_gemm, dim3(MROWS / 256 * 16), dim3(512), 0, stream,
                           cur, WyT, P16, by, out, nxt, i);
    }
}